// Round 1
// baseline (624.801 us; speedup 1.0000x reference)
//
#include <hip/hip_runtime.h>
#include <math.h>

namespace {
constexpr int DIN   = 36;
constexpr int DOUT  = 34;
constexpr int BATCH = 8;
constexpr int TOTAL = BATCH * DOUT * DOUT * DOUT;   // 314432 outputs
constexpr int ROW   = DIN;                          // innermost row length (floats)
}

__global__ __launch_bounds__(256, 4)
void lasl_kernel(const float* __restrict__ xr, const float* __restrict__ xi,
                 const float* __restrict__ wr, const float* __restrict__ wi,
                 const float* __restrict__ br, const float* __restrict__ bi,
                 const float* __restrict__ hw, const float* __restrict__ hb,
                 float* __restrict__ out)
{
    // Stage channel-0 weights + head into LDS (broadcast reads later).
    __shared__ float s_wr[81], s_wi[81], s_hw[DOUT], s_scal[3];
    const int t = threadIdx.x;
    if (t < 81)                       { s_wr[t] = wr[t]; s_wi[t] = wi[t]; }
    else if (t >= 96 && t < 96+DOUT)  { s_hw[t-96] = hw[t-96]; }
    else if (t == 160)                { s_scal[0] = br[0]; s_scal[1] = bi[0]; s_scal[2] = hb[0]; }
    __syncthreads();

    const int tid = blockIdx.x * 256 + t;
    if (tid >= TOTAL) return;

    int f = tid % DOUT;
    int r = tid / DOUT;
    int e = r % DOUT;  r /= DOUT;
    int d = r % DOUT;
    int b = r / DOUT;

    const float c_br = s_scal[0];
    const float c_bi = s_scal[1];
    float h          = s_scal[2];

    // flat index of (b, d, e, f) in the 36^3 "row grid"; row start = idx3 * 36
    const size_t idx3 = (((size_t)b * DIN + d) * DIN + e) * DIN + f;

    // Two w-halves of 17 to keep accumulator register pressure low.
    #pragma unroll
    for (int half = 0; half < 2; ++half)
    {
        const int w0 = half * 17;
        float yr[17], yi[17];
        #pragma unroll
        for (int w = 0; w < 17; ++w) { yr[w] = c_br; yi[w] = c_bi; }

        // 27 (i,j,k) tap rows; keep this loop rolled (I-cache) — inner l/w unrolled.
        #pragma unroll 1
        for (int i = 0; i < 3; ++i)
        #pragma unroll 1
        for (int j = 0; j < 3; ++j)
        #pragma unroll 1
        for (int k = 0; k < 3; ++k)
        {
            const size_t roff = (idx3 + (size_t)(i*(DIN*DIN) + j*DIN + k)) * ROW
                              + (size_t)half * 16;
            float4 bufr[5], bufi[5];
            const float4* pr = reinterpret_cast<const float4*>(xr + roff);
            const float4* pi = reinterpret_cast<const float4*>(xi + roff);
            #pragma unroll
            for (int q = 0; q < 5; ++q) { bufr[q] = pr[q]; bufi[q] = pi[q]; }
            const float* rr = reinterpret_cast<const float*>(bufr);
            const float* ri = reinterpret_cast<const float*>(bufi);

            const int tap = ((i*3 + j)*3 + k)*3;
            #pragma unroll
            for (int l = 0; l < 3; ++l)
            {
                const float wrl = s_wr[tap + l];
                const float wil = s_wi[tap + l];
                #pragma unroll
                for (int w = 0; w < 17; ++w)
                {
                    const int idx = w + l + half;   // buffer-local element index
                    yr[w] = fmaf(ri[idx], -wil, fmaf(rr[idx], wrl, yr[w]));
                    yi[w] = fmaf(ri[idx],  wrl, fmaf(rr[idx], wil, yi[w]));
                }
            }
        }

        // CReLU -> modulus -> head dot-product (partial over this half)
        #pragma unroll
        for (int w = 0; w < 17; ++w)
        {
            float a = fmaxf(yr[w], 0.0f);
            float c = fmaxf(yi[w], 0.0f);
            float m = sqrtf(fmaf(a, a, fmaf(c, c, 1e-12f)));
            h = fmaf(m, s_hw[w0 + w], h);
        }
    }

    out[tid] = 1.0f / (1.0f + __expf(-h));
}

extern "C" void kernel_launch(void* const* d_in, const int* in_sizes, int n_in,
                              void* d_out, int out_size, void* d_ws, size_t ws_size,
                              hipStream_t stream)
{
    const float* xr = (const float*)d_in[0];
    const float* xi = (const float*)d_in[1];
    const float* wr = (const float*)d_in[2];
    const float* wi = (const float*)d_in[3];
    const float* br = (const float*)d_in[4];
    const float* bi = (const float*)d_in[5];
    const float* hw = (const float*)d_in[6];
    const float* hb = (const float*)d_in[7];
    float* out = (float*)d_out;

    const int grid = (TOTAL + 255) / 256;
    lasl_kernel<<<grid, 256, 0, stream>>>(xr, xi, wr, wi, br, bi, hw, hb, out);
}